// Round 2
// baseline (623.770 us; speedup 1.0000x reference)
//
#include <hip/hip_runtime.h>
#include <math.h>

#define BB 4
#define NN 2000
#define KK 5
#define DD 32
#define H1 160
#define HEAD 5
#define HDIM 32
#define MAXNORM 0.996f
#define MINN 1e-15f

// 12000 blocks total = 6 * 2000: every 6th block does g-work (VALU-bound),
// the other 5/6 scan one-hot rows (HBM-bound). Uniform mixing hides the
// transcendental-heavy g chains under the bandwidth-bound scan.
#define TOTAL_BLOCKS 12000

typedef float vfloat4 __attribute__((ext_vector_type(4)));

__device__ __forceinline__ float artanh_f(float x) {
    x = fminf(fmaxf(x, -1.0f + 1e-7f), 1.0f - 1e-7f);
    return 0.5f * (log1pf(x) - log1pf(-x));
}

// sum over a full 64-lane wave
__device__ __forceinline__ float wave_sum(float v) {
#pragma unroll
    for (int o = 32; o > 0; o >>= 1) v += __shfl_xor(v, o, 64);
    return v;
}

// sum within each 32-lane half (both halves hold identical data in our usage)
__device__ __forceinline__ float wave_sum32(float v) {
#pragma unroll
    for (int o = 16; o > 0; o >>= 1) v += __shfl_xor(v, o, 64);
    return v;
}

// ---------------- find_idx work: FULL-STREAM one-hot search, wave per row ----
// No early exit: all 8 chunk loads are issued independently (8 KB in flight
// per wave -> ~64 MB chip-wide at 32 waves/CU), so the scan runs at the HBM
// BW roofline instead of serializing ~4.4 dependent HBM round-trips per row.
// Reads 320 MB total (vs 176 MB for early-exit) but ~3x faster wall-clock.
__device__ __forceinline__ void do_find_idx(const float* __restrict__ nei,
                                            int* __restrict__ idx,
                                            int wave, int lane) {
    const float* row = nei + (size_t)wave * NN;
    int pos = -1;
#pragma unroll
    for (int it = 0; it < 8; ++it) {
        int base = it * 256 + lane * 4;
        if (base < NN) {  // NN divisible by 4, base multiple of 4 -> float4 safe
            vfloat4 v = *(const vfloat4*)(row + base);
            if (v[0] > 0.5f) pos = base;
            if (v[1] > 0.5f) pos = base + 1;
            if (v[2] > 0.5f) pos = base + 2;
            if (v[3] > 0.5f) pos = base + 3;
        }
    }
    // exactly one lane found the 1.0; max-reduce the position across the wave
#pragma unroll
    for (int o = 32; o > 0; o >>= 1) pos = max(pos, __shfl_xor(pos, o, 64));
    if (lane == 0) idx[wave] = pos;
}

// ---------------- g work: g[row,0:160] = logmap0(hnn1(proj(expmap0(logmap0(x))))) ----
// Analytic-norm chain: |expmap0(u)| = tanh(|u|), |logmap0(p)| = artanh(|p|),
// |proj(x)| = min(|x|, MAXNORM), |s*x| = s*|x|. Only 6 reductions are genuine
// (input norm, matvec norm, bias norm, mobius cross term, mobius output, post-relu).
__device__ __forceinline__ void do_g(const float* __restrict__ xin,
                                     const float* __restrict__ W1,
                                     const float* __restrict__ b1,
                                     float* __restrict__ g,
                                     int wave, int lane) {
    bool j2ok = lane < (H1 - 128);  // lane < 32 handles third chunk

    // --- load agent row (lanes 0..31 hold components) ---
    float x = (lane < DD) ? xin[wave * DD + lane] : 0.f;

    // feats = logmap0(x)
    float n = fmaxf(sqrtf(wave_sum(x * x)), MINN);          // reduce #1
    float fa = artanh_f(n);
    float f = (fa / n) * x;
    // p = proj(expmap0(feats));  |f| = artanh(n), |p| = tanh(|f|)
    float fn = fmaxf(fa, MINN);
    float tp = tanhf(fn);
    float p = (tp / fn) * f;
    float pn = tp;
    if (pn > MAXNORM) p *= MAXNORM / pn;
    float xn = fmaxf(fminf(pn, MAXNORM), MINN);             // |p| after proj

    // mx = W1 @ p  (each lane: rows lane, lane+64, lane+128)
    float mx0 = 0.f, mx1 = 0.f, mx2 = 0.f;
#pragma unroll
    for (int d = 0; d < DD; ++d) {
        float pd = __shfl(p, d, 64);
        mx0 += W1[lane * DD + d] * pd;
        mx1 += W1[(lane + 64) * DD + d] * pd;
        if (j2ok) mx2 += W1[(lane + 128) * DD + d] * pd;
    }
    float m2 = mx0 * mx0 + mx1 * mx1 + (j2ok ? mx2 * mx2 : 0.f);
    float mxn = fmaxf(sqrtf(wave_sum(m2)), MINN);           // reduce #2
    float tr = tanhf(mxn / xn * artanh_f(xn));
    float sc = tr / mxn;
    float r0 = sc * mx0, r1 = sc * mx1, r2 = sc * mx2;
    // proj: |r| = tr (tanh arg positive)
    float rn = tr;
    if (rn > MAXNORM) { float s = MAXNORM / rn; r0 *= s; r1 *= s; r2 *= s; }
    rn = fminf(rn, MAXNORM);

    // hb = proj(expmap0(b1))  (b1 == 0 in practice; general path kept)
    float bb0 = b1[lane], bb1 = b1[lane + 64], bb2 = j2ok ? b1[lane + 128] : 0.f;
    float bn = fmaxf(sqrtf(wave_sum(bb0 * bb0 + bb1 * bb1 + bb2 * bb2)), MINN);  // reduce #3
    float tb = tanhf(bn);
    float bs = tb / bn;
    float h0 = bs * bb0, h1 = bs * bb1, h2 = bs * bb2;
    float hn = tb;
    if (hn > MAXNORM) { float s = MAXNORM / hn; h0 *= s; h1 *= s; h2 *= s; }
    hn = fminf(hn, MAXNORM);

    // mobius_add(r, h): x2s = rn^2, y2s = hn^2 analytic; only cross term reduced
    float x2s = rn * rn;
    float y2s = hn * hn;
    float xys = wave_sum(r0 * h0 + r1 * h1 + (j2ok ? r2 * h2 : 0.f));  // reduce #4
    float ca = 1.f + 2.f * xys + y2s;
    float cb = 1.f - x2s;
    float den = fmaxf(1.f + 2.f * xys + x2s * y2s, MINN);
    float a0 = (ca * r0 + cb * h0) / den;
    float a1 = (ca * r1 + cb * h1) / den;
    float a2 = (ca * r2 + cb * h2) / den;
    // proj
    float an = fmaxf(sqrtf(wave_sum(a0 * a0 + a1 * a1 + (j2ok ? a2 * a2 : 0.f))), MINN);  // reduce #5
    if (an > MAXNORM) { float s = MAXNORM / an; a0 *= s; a1 *= s; a2 *= s; }
    float an2 = fmaxf(fminf(an, MAXNORM), MINN);

    // xt = relu(logmap0(a)) — relu changes the norm, so reduce again
    float ls = artanh_f(an2) / an2;
    float t0 = fmaxf(ls * a0, 0.f), t1 = fmaxf(ls * a1, 0.f), t2 = fmaxf(ls * a2, 0.f);
    float tn = fmaxf(sqrtf(wave_sum(t0 * t0 + t1 * t1 + (j2ok ? t2 * t2 : 0.f))), MINN);  // reduce #6
    // y = proj(expmap0(xt)); |y| = tanh(tn); g = logmap0(y)
    float te = tanhf(tn);
    float es = te / tn;
    float y0 = es * t0, y1 = es * t1, y2 = es * t2;
    float yn = te;
    float s2 = (yn > MAXNORM) ? (MAXNORM / yn) : 1.f;
    y0 *= s2; y1 *= s2; y2 *= s2;
    float yn2 = fmaxf(fminf(yn, MAXNORM), MINN);
    float gs = artanh_f(yn2) / yn2;

    float* go = g + (size_t)wave * H1;
    go[lane] = gs * y0;
    go[lane + 64] = gs * y1;
    if (j2ok) go[lane + 128] = gs * y2;
}

// ---------------- Kernel 1: heterogeneous grid, 5:1 interleaved ----
// __launch_bounds__(256, 8): 8 blocks/CU (VGPR <= 64) so the BW-bound scan
// keeps 32 waves/CU (~256 KB of loads in flight per CU).
__global__ __launch_bounds__(256, 8) void scan_and_g_kernel(const float* __restrict__ nei,
                                                            int* __restrict__ idx,
                                                            const float* __restrict__ xin,
                                                            const float* __restrict__ W1,
                                                            const float* __restrict__ b1,
                                                            float* __restrict__ g) {
    int lane = threadIdx.x & 63;
    int waveInBlock = threadIdx.x >> 6;
    unsigned bi = blockIdx.x;
    unsigned q6 = bi / 6u;
    unsigned r6 = bi - q6 * 6u;
    if (r6 == 5u) {
        int wave = (int)q6 * 4 + waveInBlock;             // 0..7999
        do_g(xin, W1, b1, g, wave, lane);
    } else {
        int wave = (int)(q6 * 5u + r6) * 4 + waveInBlock; // 0..39999
        do_find_idx(nei, idx, wave, lane);
    }
}

// ---------------- Kernel 2: fused attention + output layer, wave per (b,n) --
__global__ __launch_bounds__(256, 4) void fused_att_out_kernel(const float* __restrict__ g,
                                                               const int* __restrict__ idx,
                                                               const float* __restrict__ W2,
                                                               const float* __restrict__ b2,
                                                               float* __restrict__ out,
                                                               float* __restrict__ att_out) {
    int wave = (blockIdx.x * blockDim.x + threadIdx.x) >> 6;
    int lane = threadIdx.x & 63;
    if (wave >= BB * NN) return;
    int r = wave;
    int b = r / NN;
    int d = lane & 31;  // both 32-halves do identical work

    // q[d][h]
    const float* gq = g + (size_t)r * H1;
    float q[HEAD];
#pragma unroll
    for (int h = 0; h < HEAD; ++h) q[h] = gq[d * HEAD + h];

    // load all 5 neighbor indices, then all 5 kv rows (max memory parallelism),
    // then reduce the 25 dot products
    int nb[KK];
#pragma unroll
    for (int k = 0; k < KK; ++k) nb[k] = idx[r * KK + k];
    float kv[KK][HEAD];
#pragma unroll
    for (int k = 0; k < KK; ++k) {
        const float* gk = g + (size_t)(b * NN + nb[k]) * H1 + d * HEAD;
#pragma unroll
        for (int h = 0; h < HEAD; ++h) kv[k][h] = gk[h];
    }
    float s[KK][HEAD];
#pragma unroll
    for (int k = 0; k < KK; ++k)
#pragma unroll
        for (int h = 0; h < HEAD; ++h) s[k][h] = wave_sum32(q[h] * kv[k][h]);

    // softmax over k per head (redundant per lane; all lanes hold s)
    float att[HEAD][KK];
#pragma unroll
    for (int h = 0; h < HEAD; ++h) {
        float mxv = s[0][h];
#pragma unroll
        for (int k = 1; k < KK; ++k) mxv = fmaxf(mxv, s[k][h]);
        float sum = 0.f;
#pragma unroll
        for (int k = 0; k < KK; ++k) { att[h][k] = expf(s[k][h] - mxv); sum += att[h][k]; }
        float inv = 1.f / sum;
#pragma unroll
        for (int k = 0; k < KK; ++k) att[h][k] *= inv;
    }
    // att_record: [r][h][k], lanes 0..24 write
    if (lane < HEAD * KK) {
        int h = lane / KK, k = lane % KK;
        att_out[(size_t)r * HEAD * KK + lane] = att[h][k];
    }

    // o[d] = mean over heads of sum_k att*kv
    float o = 0.f;
#pragma unroll
    for (int h = 0; h < HEAD; ++h)
#pragma unroll
        for (int k = 0; k < KK; ++k) o += att[h][k] * kv[k][h];
    o *= (1.f / HEAD);

    // ---- proj(expmap0(o)); |expmap0(o)| = tanh(|o|) ----
    float n = fmaxf(sqrtf(wave_sum32(o * o)), MINN);        // reduce #1
    float to = tanhf(n);
    o *= to / n;
    float on = to;
    if (on > MAXNORM) o *= MAXNORM / on;
    float xn = fmaxf(fminf(on, MAXNORM), MINN);

    // ---- hnn_layer(o, W2, b2) ----
    // mx[j] = W2[j,:] @ o  (j = lane&31)
    float mx = 0.f;
#pragma unroll
    for (int dd = 0; dd < HDIM; ++dd) {
        float od = __shfl(o, dd, 64);
        mx += W2[d * HDIM + dd] * od;
    }
    float mxn = fmaxf(sqrtf(wave_sum32(mx * mx)), MINN);    // reduce #2
    float tr = tanhf(mxn / xn * artanh_f(xn));
    mx *= tr / mxn;
    float rn = tr;
    if (rn > MAXNORM) mx *= MAXNORM / rn;
    rn = fminf(rn, MAXNORM);

    // hb = proj(expmap0(b2))
    float hb = b2[d];
    float bn = fmaxf(sqrtf(wave_sum32(hb * hb)), MINN);     // reduce #3
    float tb = tanhf(bn);
    hb *= tb / bn;
    float hn = tb;
    if (hn > MAXNORM) hb *= MAXNORM / hn;
    hn = fminf(hn, MAXNORM);

    // mobius_add(mx, hb): x2s/y2s analytic, cross term reduced
    float x2s = rn * rn;
    float y2s = hn * hn;
    float xys = wave_sum32(mx * hb);                        // reduce #4
    float ca = 1.f + 2.f * xys + y2s;
    float cb = 1.f - x2s;
    float den = fmaxf(1.f + 2.f * xys + x2s * y2s, MINN);
    float a = (ca * mx + cb * hb) / den;
    // proj
    float an = fmaxf(sqrtf(wave_sum32(a * a)), MINN);       // reduce #5
    if (an > MAXNORM) a *= MAXNORM / an;
    float an2 = fmaxf(fminf(an, MAXNORM), MINN);

    // xt = relu(logmap0(a))
    a = fmaxf((artanh_f(an2) / an2) * a, 0.f);
    // proj(expmap0(xt)); |expmap0(xt)| = tanh(|xt|)
    float tn = fmaxf(sqrtf(wave_sum32(a * a)), MINN);       // reduce #6
    float te = tanhf(tn);
    a *= te / tn;
    float yn = te;
    if (yn > MAXNORM) a *= MAXNORM / yn;

    if (lane < HDIM) out[(size_t)r * HDIM + lane] = a;
}

extern "C" void kernel_launch(void* const* d_in, const int* in_sizes, int n_in,
                              void* d_out, int out_size, void* d_ws, size_t ws_size,
                              hipStream_t stream) {
    const float* in_feats = (const float*)d_in[0];
    const float* in_nei = (const float*)d_in[1];
    const float* W1 = (const float*)d_in[2];
    const float* b1 = (const float*)d_in[3];
    const float* W2 = (const float*)d_in[4];
    const float* b2 = (const float*)d_in[5];

    // workspace layout: idx[40000] ints, then g[8000*160] floats
    int* idx = (int*)d_ws;
    size_t idx_bytes = ((size_t)BB * NN * KK * sizeof(int) + 255) & ~(size_t)255;
    float* g = (float*)((char*)d_ws + idx_bytes);

    float* out = (float*)d_out;                      // [B,N,32] = 256000 floats
    float* att = out + (size_t)BB * NN * HDIM;       // [B,N,head,K] = 200000 floats

    // Kernel 1: 12000 blocks, every 6th is a g-block (5:1 scan:g interleave)
    hipLaunchKernelGGL(scan_and_g_kernel, dim3(TOTAL_BLOCKS), dim3(256), 0, stream,
                       in_nei, idx, in_feats, W1, b1, g);
    // Kernel 2: fused attention + output layer, wave per (b,n)
    hipLaunchKernelGGL(fused_att_out_kernel, dim3((BB * NN * 64 + 255) / 256), dim3(256), 0, stream,
                       g, idx, W2, b2, out, att);
}

// Round 3
// 532.480 us; speedup vs baseline: 1.1714x; 1.1714x over previous
//
#include <hip/hip_runtime.h>
#include <math.h>

#define BB 4
#define NN 2000
#define KK 5
#define DD 32
#define H1 160
#define HEAD 5
#define HDIM 32
#define MAXNORM 0.996f
#define MINN 1e-15f

// ---- streaming scan geometry ----
// in_nei is [B*N*K = 40000][N = 2000] floats = 80,000,000 floats = 20,000,000 float4.
#define NROWS (BB * NN * KK)        // 40000
#define NF4   (NROWS * (NN / 4))    // 20,000,000 float4 elements
#define F4_PER_ROW (NN / 4)         // 500
#define G_BLOCKS 2000               // 8000 g-rows, 4 waves/block — launched FIRST
#define SCAN_BLOCKS 9766            // ceil(NF4 / (256*8)) -> 8 float4 per thread
#define SCAN_STRIDE (SCAN_BLOCKS * 256)  // 2,500,096 float4 between a thread's loads

typedef float vfloat4 __attribute__((ext_vector_type(4)));

__device__ __forceinline__ float artanh_f(float x) {
    x = fminf(fmaxf(x, -1.0f + 1e-7f), 1.0f - 1e-7f);
    return 0.5f * (log1pf(x) - log1pf(-x));
}

// sum over a full 64-lane wave
__device__ __forceinline__ float wave_sum(float v) {
#pragma unroll
    for (int o = 32; o > 0; o >>= 1) v += __shfl_xor(v, o, 64);
    return v;
}

// sum within each 32-lane half (both halves hold identical data in our usage)
__device__ __forceinline__ float wave_sum32(float v) {
#pragma unroll
    for (int o = 16; o > 0; o >>= 1) v += __shfl_xor(v, o, 64);
    return v;
}

// ---------------- scan: pure stream, thread-per-float4, predicated scatter ----
// Structurally a read-memcpy (like the 6.6 TB/s fill, in reverse): 8 fully
// independent coalesced float4 loads per thread, zero cross-lane ops, zero
// inter-load dependencies. Hits are 0.2% of float4s; on a hit, compute
// (row, col) and write idx[row] (one-hot => exactly one writer per row).
__device__ __forceinline__ void do_scan(const float* __restrict__ nei,
                                        int* __restrict__ idx,
                                        unsigned t) {
    const vfloat4* __restrict__ p = (const vfloat4*)nei;
    vfloat4 v[8];
#pragma unroll
    for (int j = 0; j < 8; ++j) {
        unsigned e = t + (unsigned)j * SCAN_STRIDE;
        if (e < NF4) v[j] = p[e];
    }
#pragma unroll
    for (int j = 0; j < 8; ++j) {
        unsigned e = t + (unsigned)j * SCAN_STRIDE;
        if (e < NF4) {
            int sub = -1;
            if (v[j][0] > 0.5f) sub = 0;
            if (v[j][1] > 0.5f) sub = 1;
            if (v[j][2] > 0.5f) sub = 2;
            if (v[j][3] > 0.5f) sub = 3;
            if (sub >= 0) {
                unsigned row = e / F4_PER_ROW;              // magic-mul division
                unsigned col = (e - row * F4_PER_ROW) * 4u + (unsigned)sub;
                idx[row] = (int)col;
            }
        }
    }
}

// ---------------- g work: g[row,0:160] = logmap0(hnn1(proj(expmap0(logmap0(x))))) ----
// Analytic-norm chain: |expmap0(u)| = tanh(|u|), |logmap0(p)| = artanh(|p|),
// |proj(x)| = min(|x|, MAXNORM), |s*x| = s*|x|. Only 6 reductions are genuine.
__device__ __forceinline__ void do_g(const float* __restrict__ xin,
                                     const float* __restrict__ W1,
                                     const float* __restrict__ b1,
                                     float* __restrict__ g,
                                     int wave, int lane) {
    bool j2ok = lane < (H1 - 128);  // lane < 32 handles third chunk

    // --- load agent row (lanes 0..31 hold components) ---
    float x = (lane < DD) ? xin[wave * DD + lane] : 0.f;

    // feats = logmap0(x)
    float n = fmaxf(sqrtf(wave_sum(x * x)), MINN);          // reduce #1
    float fa = artanh_f(n);
    float f = (fa / n) * x;
    // p = proj(expmap0(feats));  |f| = artanh(n), |p| = tanh(|f|)
    float fn = fmaxf(fa, MINN);
    float tp = tanhf(fn);
    float p = (tp / fn) * f;
    float pn = tp;
    if (pn > MAXNORM) p *= MAXNORM / pn;
    float xn = fmaxf(fminf(pn, MAXNORM), MINN);             // |p| after proj

    // mx = W1 @ p  (each lane: rows lane, lane+64, lane+128)
    float mx0 = 0.f, mx1 = 0.f, mx2 = 0.f;
#pragma unroll
    for (int d = 0; d < DD; ++d) {
        float pd = __shfl(p, d, 64);
        mx0 += W1[lane * DD + d] * pd;
        mx1 += W1[(lane + 64) * DD + d] * pd;
        if (j2ok) mx2 += W1[(lane + 128) * DD + d] * pd;
    }
    float m2 = mx0 * mx0 + mx1 * mx1 + (j2ok ? mx2 * mx2 : 0.f);
    float mxn = fmaxf(sqrtf(wave_sum(m2)), MINN);           // reduce #2
    float tr = tanhf(mxn / xn * artanh_f(xn));
    float sc = tr / mxn;
    float r0 = sc * mx0, r1 = sc * mx1, r2 = sc * mx2;
    // proj: |r| = tr (tanh arg positive)
    float rn = tr;
    if (rn > MAXNORM) { float s = MAXNORM / rn; r0 *= s; r1 *= s; r2 *= s; }
    rn = fminf(rn, MAXNORM);

    // hb = proj(expmap0(b1))  (b1 == 0 in practice; general path kept)
    float bb0 = b1[lane], bb1 = b1[lane + 64], bb2 = j2ok ? b1[lane + 128] : 0.f;
    float bn = fmaxf(sqrtf(wave_sum(bb0 * bb0 + bb1 * bb1 + bb2 * bb2)), MINN);  // reduce #3
    float tb = tanhf(bn);
    float bs = tb / bn;
    float h0 = bs * bb0, h1 = bs * bb1, h2 = bs * bb2;
    float hn = tb;
    if (hn > MAXNORM) { float s = MAXNORM / hn; h0 *= s; h1 *= s; h2 *= s; }
    hn = fminf(hn, MAXNORM);

    // mobius_add(r, h): x2s = rn^2, y2s = hn^2 analytic; only cross term reduced
    float x2s = rn * rn;
    float y2s = hn * hn;
    float xys = wave_sum(r0 * h0 + r1 * h1 + (j2ok ? r2 * h2 : 0.f));  // reduce #4
    float ca = 1.f + 2.f * xys + y2s;
    float cb = 1.f - x2s;
    float den = fmaxf(1.f + 2.f * xys + x2s * y2s, MINN);
    float a0 = (ca * r0 + cb * h0) / den;
    float a1 = (ca * r1 + cb * h1) / den;
    float a2 = (ca * r2 + cb * h2) / den;
    // proj
    float an = fmaxf(sqrtf(wave_sum(a0 * a0 + a1 * a1 + (j2ok ? a2 * a2 : 0.f))), MINN);  // reduce #5
    if (an > MAXNORM) { float s = MAXNORM / an; a0 *= s; a1 *= s; a2 *= s; }
    float an2 = fmaxf(fminf(an, MAXNORM), MINN);

    // xt = relu(logmap0(a)) — relu changes the norm, so reduce again
    float ls = artanh_f(an2) / an2;
    float t0 = fmaxf(ls * a0, 0.f), t1 = fmaxf(ls * a1, 0.f), t2 = fmaxf(ls * a2, 0.f);
    float tn = fmaxf(sqrtf(wave_sum(t0 * t0 + t1 * t1 + (j2ok ? t2 * t2 : 0.f))), MINN);  // reduce #6
    // y = proj(expmap0(xt)); |y| = tanh(tn); g = logmap0(y)
    float te = tanhf(tn);
    float es = te / tn;
    float y0 = es * t0, y1 = es * t1, y2 = es * t2;
    float yn = te;
    float s2 = (yn > MAXNORM) ? (MAXNORM / yn) : 1.f;
    y0 *= s2; y1 *= s2; y2 *= s2;
    float yn2 = fmaxf(fminf(yn, MAXNORM), MINN);
    float gs = artanh_f(yn2) / yn2;

    float* go = g + (size_t)wave * H1;
    go[lane] = gs * y0;
    go[lane + 64] = gs * y1;
    if (j2ok) go[lane + 128] = gs * y2;
}

// ---------------- Kernel 1: g blocks first (hide under scan), then pure stream ----
__global__ __launch_bounds__(256, 4) void scan_and_g_kernel(const float* __restrict__ nei,
                                                            int* __restrict__ idx,
                                                            const float* __restrict__ xin,
                                                            const float* __restrict__ W1,
                                                            const float* __restrict__ b1,
                                                            float* __restrict__ g) {
    unsigned bi = blockIdx.x;
    if (bi < G_BLOCKS) {
        int lane = threadIdx.x & 63;
        int wave = (int)bi * 4 + (int)(threadIdx.x >> 6);  // 0..7999
        do_g(xin, W1, b1, g, wave, lane);
        return;
    }
    unsigned t = (bi - G_BLOCKS) * 256u + threadIdx.x;     // 0 .. SCAN_STRIDE-1
    do_scan(nei, idx, t);
}

// ---------------- Kernel 2: fused attention + output layer, wave per (b,n) --
__global__ __launch_bounds__(256, 4) void fused_att_out_kernel(const float* __restrict__ g,
                                                               const int* __restrict__ idx,
                                                               const float* __restrict__ W2,
                                                               const float* __restrict__ b2,
                                                               float* __restrict__ out,
                                                               float* __restrict__ att_out) {
    int wave = (blockIdx.x * blockDim.x + threadIdx.x) >> 6;
    int lane = threadIdx.x & 63;
    if (wave >= BB * NN) return;
    int r = wave;
    int b = r / NN;
    int d = lane & 31;  // both 32-halves do identical work

    // q[d][h]
    const float* gq = g + (size_t)r * H1;
    float q[HEAD];
#pragma unroll
    for (int h = 0; h < HEAD; ++h) q[h] = gq[d * HEAD + h];

    // load all 5 neighbor indices, then all 5 kv rows (max memory parallelism),
    // then reduce the 25 dot products
    int nb[KK];
#pragma unroll
    for (int k = 0; k < KK; ++k) nb[k] = idx[r * KK + k];
    float kv[KK][HEAD];
#pragma unroll
    for (int k = 0; k < KK; ++k) {
        const float* gk = g + (size_t)(b * NN + nb[k]) * H1 + d * HEAD;
#pragma unroll
        for (int h = 0; h < HEAD; ++h) kv[k][h] = gk[h];
    }
    float s[KK][HEAD];
#pragma unroll
    for (int k = 0; k < KK; ++k)
#pragma unroll
        for (int h = 0; h < HEAD; ++h) s[k][h] = wave_sum32(q[h] * kv[k][h]);

    // softmax over k per head (redundant per lane; all lanes hold s)
    float att[HEAD][KK];
#pragma unroll
    for (int h = 0; h < HEAD; ++h) {
        float mxv = s[0][h];
#pragma unroll
        for (int k = 1; k < KK; ++k) mxv = fmaxf(mxv, s[k][h]);
        float sum = 0.f;
#pragma unroll
        for (int k = 0; k < KK; ++k) { att[h][k] = expf(s[k][h] - mxv); sum += att[h][k]; }
        float inv = 1.f / sum;
#pragma unroll
        for (int k = 0; k < KK; ++k) att[h][k] *= inv;
    }
    // att_record: [r][h][k], lanes 0..24 write
    if (lane < HEAD * KK) {
        int h = lane / KK, k = lane % KK;
        att_out[(size_t)r * HEAD * KK + lane] = att[h][k];
    }

    // o[d] = mean over heads of sum_k att*kv
    float o = 0.f;
#pragma unroll
    for (int h = 0; h < HEAD; ++h)
#pragma unroll
        for (int k = 0; k < KK; ++k) o += att[h][k] * kv[k][h];
    o *= (1.f / HEAD);

    // ---- proj(expmap0(o)); |expmap0(o)| = tanh(|o|) ----
    float n = fmaxf(sqrtf(wave_sum32(o * o)), MINN);        // reduce #1
    float to = tanhf(n);
    o *= to / n;
    float on = to;
    if (on > MAXNORM) o *= MAXNORM / on;
    float xn = fmaxf(fminf(on, MAXNORM), MINN);

    // ---- hnn_layer(o, W2, b2) ----
    // mx[j] = W2[j,:] @ o  (j = lane&31)
    float mx = 0.f;
#pragma unroll
    for (int dd = 0; dd < HDIM; ++dd) {
        float od = __shfl(o, dd, 64);
        mx += W2[d * HDIM + dd] * od;
    }
    float mxn = fmaxf(sqrtf(wave_sum32(mx * mx)), MINN);    // reduce #2
    float tr = tanhf(mxn / xn * artanh_f(xn));
    mx *= tr / mxn;
    float rn = tr;
    if (rn > MAXNORM) mx *= MAXNORM / rn;
    rn = fminf(rn, MAXNORM);

    // hb = proj(expmap0(b2))
    float hb = b2[d];
    float bn = fmaxf(sqrtf(wave_sum32(hb * hb)), MINN);     // reduce #3
    float tb = tanhf(bn);
    hb *= tb / bn;
    float hn = tb;
    if (hn > MAXNORM) hb *= MAXNORM / hn;
    hn = fminf(hn, MAXNORM);

    // mobius_add(mx, hb): x2s/y2s analytic, cross term reduced
    float x2s = rn * rn;
    float y2s = hn * hn;
    float xys = wave_sum32(mx * hb);                        // reduce #4
    float ca = 1.f + 2.f * xys + y2s;
    float cb = 1.f - x2s;
    float den = fmaxf(1.f + 2.f * xys + x2s * y2s, MINN);
    float a = (ca * mx + cb * hb) / den;
    // proj
    float an = fmaxf(sqrtf(wave_sum32(a * a)), MINN);       // reduce #5
    if (an > MAXNORM) a *= MAXNORM / an;
    float an2 = fmaxf(fminf(an, MAXNORM), MINN);

    // xt = relu(logmap0(a))
    a = fmaxf((artanh_f(an2) / an2) * a, 0.f);
    // proj(expmap0(xt)); |expmap0(xt)| = tanh(|xt|)
    float tn = fmaxf(sqrtf(wave_sum32(a * a)), MINN);       // reduce #6
    float te = tanhf(tn);
    a *= te / tn;
    float yn = te;
    if (yn > MAXNORM) a *= MAXNORM / yn;

    if (lane < HDIM) out[(size_t)r * HDIM + lane] = a;
}

extern "C" void kernel_launch(void* const* d_in, const int* in_sizes, int n_in,
                              void* d_out, int out_size, void* d_ws, size_t ws_size,
                              hipStream_t stream) {
    const float* in_feats = (const float*)d_in[0];
    const float* in_nei = (const float*)d_in[1];
    const float* W1 = (const float*)d_in[2];
    const float* b1 = (const float*)d_in[3];
    const float* W2 = (const float*)d_in[4];
    const float* b2 = (const float*)d_in[5];

    // workspace layout: idx[40000] ints, then g[8000*160] floats
    int* idx = (int*)d_ws;
    size_t idx_bytes = ((size_t)BB * NN * KK * sizeof(int) + 255) & ~(size_t)255;
    float* g = (float*)((char*)d_ws + idx_bytes);

    float* out = (float*)d_out;                      // [B,N,32] = 256000 floats
    float* att = out + (size_t)BB * NN * HDIM;       // [B,N,head,K] = 200000 floats

    // Kernel 1: 2000 g-blocks first (their long chains hide under the scan),
    // then 9766 pure-stream scan blocks (8 independent float4 per thread).
    hipLaunchKernelGGL(scan_and_g_kernel, dim3(G_BLOCKS + SCAN_BLOCKS), dim3(256), 0, stream,
                       in_nei, idx, in_feats, W1, b1, g);
    // Kernel 2: fused attention + output layer, wave per (b,n)
    hipLaunchKernelGGL(fused_att_out_kernel, dim3((BB * NN * 64 + 255) / 256), dim3(256), 0, stream,
                       g, idx, W2, b2, out, att);
}

// Round 4
// 519.702 us; speedup vs baseline: 1.2002x; 1.0246x over previous
//
#include <hip/hip_runtime.h>
#include <math.h>

#define BB 4
#define NN 2000
#define KK 5
#define DD 32
#define H1 160
#define HEAD 5
#define HDIM 32
#define MAXNORM 0.996f
#define MINN 1e-15f

// ---- streaming scan geometry ----
// in_nei is [B*N*K = 40000][N = 2000] floats = 80,000,000 floats = 20,000,000 float4.
#define NROWS (BB * NN * KK)        // 40000
#define NF4   (NROWS * (NN / 4))    // 20,000,000 float4 elements
#define F4_PER_ROW (NN / 4)         // 500
#define G_BLOCKS 2000               // 8000 g-rows, 4 waves/block
#define SCAN_BLOCKS 9766            // ceil(NF4 / (256*8)) -> 8 float4 per thread
#define SCAN_STRIDE (SCAN_BLOCKS * 256)  // 2,500,096 float4 between a thread's loads

typedef float vfloat4 __attribute__((ext_vector_type(4)));

__device__ __forceinline__ float artanh_f(float x) {
    x = fminf(fmaxf(x, -1.0f + 1e-7f), 1.0f - 1e-7f);
    return 0.5f * (log1pf(x) - log1pf(-x));
}

// sum over a full 64-lane wave
__device__ __forceinline__ float wave_sum(float v) {
#pragma unroll
    for (int o = 32; o > 0; o >>= 1) v += __shfl_xor(v, o, 64);
    return v;
}

// sum within each 32-lane half (both halves hold identical data in our usage)
__device__ __forceinline__ float wave_sum32(float v) {
#pragma unroll
    for (int o = 16; o > 0; o >>= 1) v += __shfl_xor(v, o, 64);
    return v;
}

// ---------------- scan kernel: pure stream, thread-per-float4, NT loads ----
// 8 fully independent coalesced float4 loads per thread, zero cross-lane ops.
// Nontemporal: the stream has zero reuse; skipping cache allocation avoids
// force-writing-back the harness fill's dirty L3 lines (~100 MB/iter observed
// as scan-attributed WRITE_SIZE in R1/R2) and keeps the g-table resident for
// the fused kernel. No launch_bounds min: let all 8 loads stay in flight.
__global__ __launch_bounds__(256) void scan_kernel(const float* __restrict__ nei,
                                                   int* __restrict__ idx) {
    unsigned t = blockIdx.x * 256u + threadIdx.x;   // 0 .. SCAN_STRIDE-1
    const vfloat4* __restrict__ p = (const vfloat4*)nei;
    vfloat4 v[8];
#pragma unroll
    for (int j = 0; j < 8; ++j) {
        unsigned e = t + (unsigned)j * SCAN_STRIDE;
        if (e < NF4) v[j] = __builtin_nontemporal_load(p + e);
    }
#pragma unroll
    for (int j = 0; j < 8; ++j) {
        unsigned e = t + (unsigned)j * SCAN_STRIDE;
        if (e < NF4) {
            int sub = -1;
            if (v[j][0] > 0.5f) sub = 0;
            if (v[j][1] > 0.5f) sub = 1;
            if (v[j][2] > 0.5f) sub = 2;
            if (v[j][3] > 0.5f) sub = 3;
            if (sub >= 0) {
                unsigned row = e / F4_PER_ROW;              // magic-mul division
                unsigned col = (e - row * F4_PER_ROW) * 4u + (unsigned)sub;
                idx[row] = (int)col;                        // one-hot: unique writer
            }
        }
    }
}

// ---------------- g kernel: g[row,0:160] = logmap0(hnn1(proj(expmap0(logmap0(x))))) ----
// Analytic-norm chain: |expmap0(u)| = tanh(|u|), |logmap0(p)| = artanh(|p|),
// |proj(x)| = min(|x|, MAXNORM), |s*x| = s*|x|. Only 6 reductions are genuine.
__global__ __launch_bounds__(256, 4) void g_kernel(const float* __restrict__ xin,
                                                   const float* __restrict__ W1,
                                                   const float* __restrict__ b1,
                                                   float* __restrict__ g) {
    int lane = threadIdx.x & 63;
    int wave = (int)blockIdx.x * 4 + (int)(threadIdx.x >> 6);  // 0..7999
    bool j2ok = lane < (H1 - 128);  // lane < 32 handles third chunk

    // --- load agent row (lanes 0..31 hold components) ---
    float x = (lane < DD) ? xin[wave * DD + lane] : 0.f;

    // feats = logmap0(x)
    float n = fmaxf(sqrtf(wave_sum(x * x)), MINN);          // reduce #1
    float fa = artanh_f(n);
    float f = (fa / n) * x;
    // p = proj(expmap0(feats));  |f| = artanh(n), |p| = tanh(|f|)
    float fn = fmaxf(fa, MINN);
    float tp = tanhf(fn);
    float p = (tp / fn) * f;
    float pn = tp;
    if (pn > MAXNORM) p *= MAXNORM / pn;
    float xn = fmaxf(fminf(pn, MAXNORM), MINN);             // |p| after proj

    // mx = W1 @ p  (each lane: rows lane, lane+64, lane+128)
    float mx0 = 0.f, mx1 = 0.f, mx2 = 0.f;
#pragma unroll
    for (int d = 0; d < DD; ++d) {
        float pd = __shfl(p, d, 64);
        mx0 += W1[lane * DD + d] * pd;
        mx1 += W1[(lane + 64) * DD + d] * pd;
        if (j2ok) mx2 += W1[(lane + 128) * DD + d] * pd;
    }
    float m2 = mx0 * mx0 + mx1 * mx1 + (j2ok ? mx2 * mx2 : 0.f);
    float mxn = fmaxf(sqrtf(wave_sum(m2)), MINN);           // reduce #2
    float tr = tanhf(mxn / xn * artanh_f(xn));
    float sc = tr / mxn;
    float r0 = sc * mx0, r1 = sc * mx1, r2 = sc * mx2;
    // proj: |r| = tr (tanh arg positive)
    float rn = tr;
    if (rn > MAXNORM) { float s = MAXNORM / rn; r0 *= s; r1 *= s; r2 *= s; }
    rn = fminf(rn, MAXNORM);

    // hb = proj(expmap0(b1))  (b1 == 0 in practice; general path kept)
    float bb0 = b1[lane], bb1 = b1[lane + 64], bb2 = j2ok ? b1[lane + 128] : 0.f;
    float bn = fmaxf(sqrtf(wave_sum(bb0 * bb0 + bb1 * bb1 + bb2 * bb2)), MINN);  // reduce #3
    float tb = tanhf(bn);
    float bs = tb / bn;
    float h0 = bs * bb0, h1 = bs * bb1, h2 = bs * bb2;
    float hn = tb;
    if (hn > MAXNORM) { float s = MAXNORM / hn; h0 *= s; h1 *= s; h2 *= s; }
    hn = fminf(hn, MAXNORM);

    // mobius_add(r, h): x2s = rn^2, y2s = hn^2 analytic; only cross term reduced
    float x2s = rn * rn;
    float y2s = hn * hn;
    float xys = wave_sum(r0 * h0 + r1 * h1 + (j2ok ? r2 * h2 : 0.f));  // reduce #4
    float ca = 1.f + 2.f * xys + y2s;
    float cb = 1.f - x2s;
    float den = fmaxf(1.f + 2.f * xys + x2s * y2s, MINN);
    float a0 = (ca * r0 + cb * h0) / den;
    float a1 = (ca * r1 + cb * h1) / den;
    float a2 = (ca * r2 + cb * h2) / den;
    // proj
    float an = fmaxf(sqrtf(wave_sum(a0 * a0 + a1 * a1 + (j2ok ? a2 * a2 : 0.f))), MINN);  // reduce #5
    if (an > MAXNORM) { float s = MAXNORM / an; a0 *= s; a1 *= s; a2 *= s; }
    float an2 = fmaxf(fminf(an, MAXNORM), MINN);

    // xt = relu(logmap0(a)) — relu changes the norm, so reduce again
    float ls = artanh_f(an2) / an2;
    float t0 = fmaxf(ls * a0, 0.f), t1 = fmaxf(ls * a1, 0.f), t2 = fmaxf(ls * a2, 0.f);
    float tn = fmaxf(sqrtf(wave_sum(t0 * t0 + t1 * t1 + (j2ok ? t2 * t2 : 0.f))), MINN);  // reduce #6
    // y = proj(expmap0(xt)); |y| = tanh(tn); g = logmap0(y)
    float te = tanhf(tn);
    float es = te / tn;
    float y0 = es * t0, y1 = es * t1, y2 = es * t2;
    float yn = te;
    float s2 = (yn > MAXNORM) ? (MAXNORM / yn) : 1.f;
    y0 *= s2; y1 *= s2; y2 *= s2;
    float yn2 = fmaxf(fminf(yn, MAXNORM), MINN);
    float gs = artanh_f(yn2) / yn2;

    float* go = g + (size_t)wave * H1;
    go[lane] = gs * y0;
    go[lane + 64] = gs * y1;
    if (j2ok) go[lane + 128] = gs * y2;
}

// ---------------- Kernel 3: fused attention + output layer, wave per (b,n) --
__global__ __launch_bounds__(256, 4) void fused_att_out_kernel(const float* __restrict__ g,
                                                               const int* __restrict__ idx,
                                                               const float* __restrict__ W2,
                                                               const float* __restrict__ b2,
                                                               float* __restrict__ out,
                                                               float* __restrict__ att_out) {
    int wave = (blockIdx.x * blockDim.x + threadIdx.x) >> 6;
    int lane = threadIdx.x & 63;
    if (wave >= BB * NN) return;
    int r = wave;
    int b = r / NN;
    int d = lane & 31;  // both 32-halves do identical work

    // q[d][h]
    const float* gq = g + (size_t)r * H1;
    float q[HEAD];
#pragma unroll
    for (int h = 0; h < HEAD; ++h) q[h] = gq[d * HEAD + h];

    // load all 5 neighbor indices, then all 5 kv rows (max memory parallelism),
    // then reduce the 25 dot products
    int nb[KK];
#pragma unroll
    for (int k = 0; k < KK; ++k) nb[k] = idx[r * KK + k];
    float kv[KK][HEAD];
#pragma unroll
    for (int k = 0; k < KK; ++k) {
        const float* gk = g + (size_t)(b * NN + nb[k]) * H1 + d * HEAD;
#pragma unroll
        for (int h = 0; h < HEAD; ++h) kv[k][h] = gk[h];
    }
    float s[KK][HEAD];
#pragma unroll
    for (int k = 0; k < KK; ++k)
#pragma unroll
        for (int h = 0; h < HEAD; ++h) s[k][h] = wave_sum32(q[h] * kv[k][h]);

    // softmax over k per head (redundant per lane; all lanes hold s)
    float att[HEAD][KK];
#pragma unroll
    for (int h = 0; h < HEAD; ++h) {
        float mxv = s[0][h];
#pragma unroll
        for (int k = 1; k < KK; ++k) mxv = fmaxf(mxv, s[k][h]);
        float sum = 0.f;
#pragma unroll
        for (int k = 0; k < KK; ++k) { att[h][k] = expf(s[k][h] - mxv); sum += att[h][k]; }
        float inv = 1.f / sum;
#pragma unroll
        for (int k = 0; k < KK; ++k) att[h][k] *= inv;
    }
    // att_record: [r][h][k], lanes 0..24 write
    if (lane < HEAD * KK) {
        int h = lane / KK, k = lane % KK;
        att_out[(size_t)r * HEAD * KK + lane] = att[h][k];
    }

    // o[d] = mean over heads of sum_k att*kv
    float o = 0.f;
#pragma unroll
    for (int h = 0; h < HEAD; ++h)
#pragma unroll
        for (int k = 0; k < KK; ++k) o += att[h][k] * kv[k][h];
    o *= (1.f / HEAD);

    // ---- proj(expmap0(o)); |expmap0(o)| = tanh(|o|) ----
    float n = fmaxf(sqrtf(wave_sum32(o * o)), MINN);        // reduce #1
    float to = tanhf(n);
    o *= to / n;
    float on = to;
    if (on > MAXNORM) o *= MAXNORM / on;
    float xn = fmaxf(fminf(on, MAXNORM), MINN);

    // ---- hnn_layer(o, W2, b2) ----
    // mx[j] = W2[j,:] @ o  (j = lane&31)
    float mx = 0.f;
#pragma unroll
    for (int dd = 0; dd < HDIM; ++dd) {
        float od = __shfl(o, dd, 64);
        mx += W2[d * HDIM + dd] * od;
    }
    float mxn = fmaxf(sqrtf(wave_sum32(mx * mx)), MINN);    // reduce #2
    float tr = tanhf(mxn / xn * artanh_f(xn));
    mx *= tr / mxn;
    float rn = tr;
    if (rn > MAXNORM) mx *= MAXNORM / rn;
    rn = fminf(rn, MAXNORM);

    // hb = proj(expmap0(b2))
    float hb = b2[d];
    float bn = fmaxf(sqrtf(wave_sum32(hb * hb)), MINN);     // reduce #3
    float tb = tanhf(bn);
    hb *= tb / bn;
    float hn = tb;
    if (hn > MAXNORM) hb *= MAXNORM / hn;
    hn = fminf(hn, MAXNORM);

    // mobius_add(mx, hb): x2s/y2s analytic, cross term reduced
    float x2s = rn * rn;
    float y2s = hn * hn;
    float xys = wave_sum32(mx * hb);                        // reduce #4
    float ca = 1.f + 2.f * xys + y2s;
    float cb = 1.f - x2s;
    float den = fmaxf(1.f + 2.f * xys + x2s * y2s, MINN);
    float a = (ca * mx + cb * hb) / den;
    // proj
    float an = fmaxf(sqrtf(wave_sum32(a * a)), MINN);       // reduce #5
    if (an > MAXNORM) a *= MAXNORM / an;
    float an2 = fmaxf(fminf(an, MAXNORM), MINN);

    // xt = relu(logmap0(a))
    a = fmaxf((artanh_f(an2) / an2) * a, 0.f);
    // proj(expmap0(xt)); |expmap0(xt)| = tanh(|xt|)
    float tn = fmaxf(sqrtf(wave_sum32(a * a)), MINN);       // reduce #6
    float te = tanhf(tn);
    a *= te / tn;
    float yn = te;
    if (yn > MAXNORM) a *= MAXNORM / yn;

    if (lane < HDIM) out[(size_t)r * HDIM + lane] = a;
}

extern "C" void kernel_launch(void* const* d_in, const int* in_sizes, int n_in,
                              void* d_out, int out_size, void* d_ws, size_t ws_size,
                              hipStream_t stream) {
    const float* in_feats = (const float*)d_in[0];
    const float* in_nei = (const float*)d_in[1];
    const float* W1 = (const float*)d_in[2];
    const float* b1 = (const float*)d_in[3];
    const float* W2 = (const float*)d_in[4];
    const float* b2 = (const float*)d_in[5];

    // workspace layout: idx[40000] ints, then g[8000*160] floats
    int* idx = (int*)d_ws;
    size_t idx_bytes = ((size_t)BB * NN * KK * sizeof(int) + 255) & ~(size_t)255;
    float* g = (float*)((char*)d_ws + idx_bytes);

    float* out = (float*)d_out;                      // [B,N,32] = 256000 floats
    float* att = out + (size_t)BB * NN * HDIM;       // [B,N,head,K] = 200000 floats

    // Three kernels, separately timed in rocprof:
    // 1) g table (short, VALU-bound), 2) NT stream scan (HBM-bound),
    // 3) fused attention + output layer (reads cache-warm g).
    hipLaunchKernelGGL(g_kernel, dim3(G_BLOCKS), dim3(256), 0, stream,
                       in_feats, W1, b1, g);
    hipLaunchKernelGGL(scan_kernel, dim3(SCAN_BLOCKS), dim3(256), 0, stream,
                       in_nei, idx);
    hipLaunchKernelGGL(fused_att_out_kernel, dim3((BB * NN * 64 + 255) / 256), dim3(256), 0, stream,
                       g, idx, W2, b2, out, att);
}